// Round 8
// baseline (350.519 us; speedup 1.0000x reference)
//
#include <hip/hip_runtime.h>

#define B_ 2
#define S_ 2048
#define D_ 1024
#define H_ 16

typedef unsigned short u16;
typedef __bf16 bf16x8 __attribute__((ext_vector_type(8)));
typedef float f32x4 __attribute__((ext_vector_type(4)));
typedef unsigned short u16x8 __attribute__((ext_vector_type(8)));

__device__ __forceinline__ unsigned swz128(unsigned o) {  // 128B rows
  return o ^ (((o >> 7) & 7) << 4);
}
__device__ __forceinline__ unsigned swz256(unsigned o) {  // 256B rows
  return o ^ (((o >> 8) & 7) << 4);
}

__device__ __forceinline__ void gload_lds16(const void* g, void* l) {
  __builtin_amdgcn_global_load_lds(
      (const __attribute__((address_space(1))) unsigned*)g,
      (__attribute__((address_space(3))) unsigned*)l, 16, 0, 0);
}

__device__ __forceinline__ u16 f2bf(float f) {
  union { float f; unsigned u; } v;
  v.f = f;
  unsigned u = v.u;
  return (u16)((u + 0x7fffu + ((u >> 16) & 1u)) >> 16);
}

// ---------------- f32 -> bf16 cast, 3 tensors batched ----------------
struct C3 { const float* in[3]; u16* out[3]; };
__global__ __launch_bounds__(256) void cast3(C3 p, int n8) {
  int z = blockIdx.y;
  int i = blockIdx.x * 256 + threadIdx.x;
  if (i >= n8) return;
  const float4* src = (const float4*)p.in[z] + (size_t)i * 2;
  float4 a = src[0], b = src[1];
  u16x8 o;
  o[0] = f2bf(a.x); o[1] = f2bf(a.y); o[2] = f2bf(a.z); o[3] = f2bf(a.w);
  o[4] = f2bf(b.x); o[5] = f2bf(b.y); o[6] = f2bf(b.z); o[7] = f2bf(b.w);
  *((u16x8*)p.out[z] + i) = o;
}

// ---------------- transpose+cast 1024x1024 f32 weights -> bf16, 4 batched ----
struct T4 { const float* in[4]; u16* out[4]; };
__global__ __launch_bounds__(256) void transpose_w4(T4 p) {
  __shared__ u16 t[64][65];
  const float* in = p.in[blockIdx.z];
  u16* out = p.out[blockIdx.z];
  int r0 = blockIdx.y * 64, c0 = blockIdx.x * 64;
  for (int i = threadIdx.x; i < 4096; i += 256) {
    int r = i >> 6, c = i & 63;
    t[r][c] = f2bf(in[(size_t)(r0 + r) * 1024 + c0 + c]);
  }
  __syncthreads();
  for (int i = threadIdx.x; i < 4096; i += 256) {
    int r = i >> 6, c = i & 63;
    out[(size_t)(c0 + r) * 1024 + r0 + c] = t[c][r];
  }
}

// ---------------- V[B,S,D](bf16) -> VT[b*H+h][64][S] ----------------
__global__ __launch_bounds__(256) void transpose_v(const u16* __restrict__ V,
                                                   u16* __restrict__ VT) {
  __shared__ u16 t[64][65];
  int s0 = blockIdx.x * 64;
  int bh = blockIdx.y, b = bh >> 4, h = bh & 15;
  const u16* src = V + (size_t)b * S_ * D_ + h * 64;
  u16* dst = VT + (size_t)bh * 64 * S_;
  for (int i = threadIdx.x; i < 4096; i += 256) {
    int s = i >> 6, dk = i & 63;
    t[s][dk] = src[(size_t)(s0 + s) * D_ + dk];
  }
  __syncthreads();
  for (int i = threadIdx.x; i < 4096; i += 256) {
    int dk = i >> 6, s = i & 63;
    dst[(size_t)dk * S_ + s0 + s] = t[s][dk];
  }
}

// ---------------- GEMM body: C[M,N] = A[M,K] * BT[N,K]^T (bf16 in) ---------
// Tile 128x64, BK=64, 4 waves (2x2). Verified structure (rounds 2-7).
template <bool OUTF32>
__device__ __forceinline__ void gemm_body(const u16* __restrict__ A,
                                          const u16* __restrict__ BT,
                                          void* __restrict__ Cv) {
  constexpr int K = 1024, N = 1024;
  __shared__ __align__(16) u16 lA[128 * 64];
  __shared__ __align__(16) u16 lB[64 * 64];
  const int tid = threadIdx.x, lane = tid & 63, w = tid >> 6;
  const int wr = w >> 1, wc = w & 1;
  const int m0 = blockIdx.x * 128, n0 = blockIdx.y * 64;
  const int g = lane >> 4, c16 = lane & 15;
  f32x4 acc[4][2] = {};
  const char* Ab = (const char*)(A + (size_t)m0 * K);
  const char* Bb = (const char*)(BT + (size_t)n0 * K);
  char* lAb = (char*)lA;
  char* lBb = (char*)lB;
  for (int kt = 0; kt < K; kt += 64) {
    for (int c = 0; c < 4; ++c) {
      unsigned o = w * 4096 + c * 1024 + lane * 16;
      unsigned u = swz128(o);
      gload_lds16(Ab + (size_t)(u >> 7) * (K * 2) + kt * 2 + (u & 127),
                  lAb + w * 4096 + c * 1024);
    }
    for (int c = 0; c < 2; ++c) {
      unsigned o = w * 2048 + c * 1024 + lane * 16;
      unsigned u = swz128(o);
      gload_lds16(Bb + (size_t)(u >> 7) * (K * 2) + kt * 2 + (u & 127),
                  lBb + w * 2048 + c * 1024);
    }
    asm volatile("s_waitcnt vmcnt(0)" ::: "memory");
    __syncthreads();
    for (int ks = 0; ks < 2; ++ks) {
      bf16x8 af[4], bf[2];
      for (int i = 0; i < 4; ++i) {
        unsigned row = wr * 64 + i * 16 + c16;
        unsigned o = row * 128 + ks * 64 + g * 16;
        af[i] = *(const bf16x8*)(lAb + (o ^ ((row & 7) << 4)));
      }
      for (int j = 0; j < 2; ++j) {
        unsigned row = wc * 32 + j * 16 + c16;
        unsigned o = row * 128 + ks * 64 + g * 16;
        bf[j] = *(const bf16x8*)(lBb + (o ^ ((row & 7) << 4)));
      }
      for (int i = 0; i < 4; ++i)
        for (int j = 0; j < 2; ++j)
          acc[i][j] = __builtin_amdgcn_mfma_f32_16x16x32_bf16(af[i], bf[j],
                                                              acc[i][j], 0, 0, 0);
    }
    __syncthreads();
  }
  for (int i = 0; i < 4; ++i)
    for (int j = 0; j < 2; ++j) {
      int row = m0 + wr * 64 + i * 16 + g * 4;
      int col = n0 + wc * 32 + j * 16 + c16;
      for (int r = 0; r < 4; ++r) {
        if constexpr (OUTF32)
          ((float*)Cv)[(size_t)(row + r) * N + col] = acc[i][j][r];
        else
          ((u16*)Cv)[(size_t)(row + r) * N + col] = f2bf(acc[i][j][r]);
      }
    }
}

struct G3 { const u16* A[3]; const u16* BT[3]; u16* C[3]; };
__global__ __launch_bounds__(256) void gemm_bt3(G3 p) {
  gemm_body<false>(p.A[blockIdx.z], p.BT[blockIdx.z], p.C[blockIdx.z]);
}
__global__ __launch_bounds__(256) void gemm_bt_f32(const u16* __restrict__ A,
                                                   const u16* __restrict__ BT,
                                                   float* __restrict__ C) {
  gemm_body<true>(A, BT, C);
}

// ---------------- flash attention v2 ----------------
// grid (S/128, B*H); 512 threads = 8 waves; wave w owns q rows [w*16, w*16+16).
// QBLK=128, KVBLK=128; K/V of tile t+1 reg-prefetched during compute of t.
__global__ __launch_bounds__(512, 4) void flash_attn(const u16* __restrict__ Q,
                                                     const u16* __restrict__ K,
                                                     const u16* __restrict__ VT,
                                                     u16* __restrict__ O) {
  __shared__ __align__(16) u16 lQ[128 * 64];    // 16KB, 128B rows
  __shared__ __align__(16) u16 lK[128 * 64];    // 16KB, 128B rows
  __shared__ __align__(16) u16 lV[64 * 128];    // 16KB, 256B rows (VT layout)
  __shared__ __align__(16) u16 lP[128 * 128];   // 32KB, 256B rows
  const int tid = threadIdx.x, lane = tid & 63, w = tid >> 6;
  const int g = lane >> 4, c16 = lane & 15;
  const int q0 = blockIdx.x * 128;
  const int bh = blockIdx.y, b = bh >> 4, h = bh & 15;
  const char* Qb = (const char*)(Q + (size_t)(b * S_ + q0) * D_ + h * 64);
  const char* Kb = (const char*)(K + (size_t)b * S_ * D_ + h * 64);
  const char* Vb = (const char*)(VT + (size_t)bh * 64 * S_);
  char* lQb = (char*)lQ;
  char* lKb = (char*)lK;
  char* lVb = (char*)lV;
  char* lPb = (char*)lP;

  // prologue: stage Q + K/V tile 0 (gload_lds, pre-swizzled source, rule #21)
  for (int c = 0; c < 2; ++c) {
    unsigned o = c * 8192 + tid * 16;
    unsigned u = swz128(o);
    gload_lds16(Qb + (size_t)(u >> 7) * (D_ * 2) + (u & 127), lQb + o);
    gload_lds16(Kb + (size_t)(u >> 7) * (D_ * 2) + (u & 127), lKb + o);
    unsigned v = swz256(o);
    gload_lds16(Vb + (size_t)(v >> 8) * (S_ * 2) + (v & 255), lVb + o);
  }
  float m_run[4], l_run[4];
  f32x4 oacc[4] = {};
  for (int r = 0; r < 4; ++r) { m_run[r] = -INFINITY; l_run[r] = 0.f; }
  asm volatile("s_waitcnt vmcnt(0)" ::: "memory");
  __syncthreads();
  bf16x8 qf[2];
  {
    unsigned row = w * 16 + c16;
    for (int ks = 0; ks < 2; ++ks) {
      unsigned o = row * 128 + ks * 64 + g * 16;
      qf[ks] = *(const bf16x8*)(lQb + swz128(o));
    }
  }
  const float SC2 = 0.125f * 1.44269504088896340736f;  // SCALE * log2(e)
  for (int kv0 = 0; kv0 < S_; kv0 += 128) {
    const bool pref = (kv0 + 128) < S_;
    u16x8 kpre[2], vpre[2];
    if (pref) {  // T14: issue next-tile global loads before compute
      for (int c = 0; c < 2; ++c) {
        unsigned o = c * 8192 + tid * 16;
        kpre[c] = *(const u16x8*)(Kb + (size_t)(kv0 + 128 + (o >> 7)) * (D_ * 2) + (o & 127));
        vpre[c] = *(const u16x8*)(Vb + (size_t)(o >> 8) * (S_ * 2) + (size_t)(kv0 + 128) * 2 + (o & 255));
      }
    }
    // S = Q K^T (128 kv cols)
    f32x4 s[8] = {};
    for (int ks = 0; ks < 2; ++ks)
      for (int j = 0; j < 8; ++j) {
        unsigned row = j * 16 + c16;
        unsigned o = row * 128 + ks * 64 + g * 16;
        bf16x8 kf = *(const bf16x8*)(lKb + swz128(o));
        s[j] = __builtin_amdgcn_mfma_f32_16x16x32_bf16(qf[ks], kf, s[j], 0, 0, 0);
      }
    // online softmax; lane holds q=w*16+g*4+r, kv=j*16+c16
    for (int r = 0; r < 4; ++r) {
      float rm = s[0][r];
      for (int j = 1; j < 8; ++j) rm = fmaxf(rm, s[j][r]);
      rm = fmaxf(rm, __shfl_xor(rm, 1));
      rm = fmaxf(rm, __shfl_xor(rm, 2));
      rm = fmaxf(rm, __shfl_xor(rm, 4));
      rm = fmaxf(rm, __shfl_xor(rm, 8));
      float mn = fmaxf(m_run[r], rm);
      float sc = exp2f((m_run[r] - mn) * SC2);
      m_run[r] = mn;
      float p[8], rs = 0.f;
      for (int j = 0; j < 8; ++j) {
        p[j] = exp2f((s[j][r] - mn) * SC2);
        rs += p[j];
      }
      rs += __shfl_xor(rs, 1);
      rs += __shfl_xor(rs, 2);
      rs += __shfl_xor(rs, 4);
      rs += __shfl_xor(rs, 8);
      l_run[r] = l_run[r] * sc + rs;
      for (int j = 0; j < 4; ++j) oacc[j][r] *= sc;
      unsigned qrow = w * 16 + g * 4 + r;
      for (int j = 0; j < 8; ++j) {
        unsigned o = qrow * 256 + (unsigned)(j * 16 + c16) * 2;
        *(u16*)(lPb + swz256(o)) = f2bf(p[j]);
      }
    }
    // O += P V (P rows wave-private: no barrier needed before PV)
    {
      unsigned prow = w * 16 + c16;
      for (int ks = 0; ks < 4; ++ks) {
        unsigned po = prow * 256 + ks * 64 + g * 16;
        bf16x8 pf = *(const bf16x8*)(lPb + swz256(po));
        for (int j = 0; j < 4; ++j) {
          unsigned vrow = j * 16 + c16;
          unsigned vo = vrow * 256 + ks * 64 + g * 16;
          bf16x8 vf = *(const bf16x8*)(lVb + swz256(vo));
          oacc[j] = __builtin_amdgcn_mfma_f32_16x16x32_bf16(pf, vf, oacc[j], 0, 0, 0);
        }
      }
    }
    __syncthreads();  // all reads of lK/lV done
    if (pref) {       // swizzle-write prefetched tile (reg-staged: dest swizzled)
      for (int c = 0; c < 2; ++c) {
        unsigned o = c * 8192 + tid * 16;
        *(u16x8*)(lKb + swz128(o)) = kpre[c];
        *(u16x8*)(lVb + swz256(o)) = vpre[c];
      }
    }
    __syncthreads();  // staged tile visible
  }
  for (int j = 0; j < 4; ++j)
    for (int r = 0; r < 4; ++r) {
      int q = q0 + w * 16 + g * 4 + r;
      int col = h * 64 + j * 16 + c16;
      O[(size_t)(b * S_ + q) * D_ + col] = f2bf(oacc[j][r] / l_run[r]);
    }
}

extern "C" void kernel_launch(void* const* d_in, const int* in_sizes, int n_in,
                              void* d_out, int out_size, void* d_ws, size_t ws_size,
                              hipStream_t stream) {
  const float* q_in = (const float*)d_in[0];
  const float* k_in = (const float*)d_in[1];
  const float* v_in = (const float*)d_in[2];
  const float* Wq = (const float*)d_in[3];
  const float* Wk = (const float*)d_in[4];
  const float* Wv = (const float*)d_in[5];
  const float* Wo = (const float*)d_in[6];
  u16* ws = (u16*)d_ws;
  const size_t WSZ = (size_t)1024 * 1024;
  const size_t TSZ = (size_t)B_ * S_ * D_;  // 4,194,304
  u16* WqT = ws;
  u16* WkT = ws + WSZ;
  u16* WvT = ws + 2 * WSZ;
  u16* WoT = ws + 3 * WSZ;
  u16* Qc = ws + 4 * WSZ;   // casted bf16 inputs
  u16* Kc = Qc + TSZ;
  u16* Vc = Kc + TSZ;
  u16* Qb = Vc + TSZ;       // projected
  u16* Kb = Qb + TSZ;
  u16* Vb = Kb + TSZ;
  u16* VTb = Kc;            // alias: Kc dead after K projection
  u16* Ob = Qc;             // alias: Qc dead after Q projection
  dim3 tb(256);
  T4 tw = {{Wq, Wk, Wv, Wo}, {WqT, WkT, WvT, WoT}};
  transpose_w4<<<dim3(16, 16, 4), tb, 0, stream>>>(tw);
  int n8 = (int)(TSZ / 8);
  C3 cc = {{q_in, k_in, v_in}, {Qc, Kc, Vc}};
  cast3<<<dim3(n8 / 256, 3), tb, 0, stream>>>(cc, n8);
  G3 gg = {{Qc, Kc, Vc}, {WqT, WkT, WvT}, {Qb, Kb, Vb}};
  gemm_bt3<<<dim3(32, 16, 3), tb, 0, stream>>>(gg);
  transpose_v<<<dim3(32, 32), tb, 0, stream>>>(Vb, VTb);
  flash_attn<<<dim3(S_ / 128, B_ * H_), dim3(512), 0, stream>>>(Qb, Kb, VTb, Ob);
  gemm_bt_f32<<<dim3(32, 16), tb, 0, stream>>>(Ob, WoT, (float*)d_out);
}

// Round 9
// 210.441 us; speedup vs baseline: 1.6656x; 1.6656x over previous
//
#include <hip/hip_runtime.h>

#define B_ 2
#define S_ 2048
#define D_ 1024
#define H_ 16

typedef unsigned short u16;
typedef __bf16 bf16x8 __attribute__((ext_vector_type(8)));
typedef float f32x4 __attribute__((ext_vector_type(4)));
typedef unsigned short u16x8 __attribute__((ext_vector_type(8)));

__device__ __forceinline__ unsigned swz128(unsigned o) {  // 128B rows
  return o ^ (((o >> 7) & 7) << 4);
}

__device__ __forceinline__ void gload_lds16(const void* g, void* l) {
  __builtin_amdgcn_global_load_lds(
      (const __attribute__((address_space(1))) unsigned*)g,
      (__attribute__((address_space(3))) unsigned*)l, 16, 0, 0);
}

__device__ __forceinline__ u16 f2bf(float f) {
  union { float f; unsigned u; } v;
  v.f = f;
  unsigned u = v.u;
  return (u16)((u + 0x7fffu + ((u >> 16) & 1u)) >> 16);
}

// ---------------- f32 -> bf16 cast, 3 tensors batched ----------------
struct C3 { const float* in[3]; u16* out[3]; };
__global__ __launch_bounds__(256) void cast3(C3 p, int n8) {
  int z = blockIdx.y;
  int i = blockIdx.x * 256 + threadIdx.x;
  if (i >= n8) return;
  const float4* src = (const float4*)p.in[z] + (size_t)i * 2;
  float4 a = src[0], b = src[1];
  u16x8 o;
  o[0] = f2bf(a.x); o[1] = f2bf(a.y); o[2] = f2bf(a.z); o[3] = f2bf(a.w);
  o[4] = f2bf(b.x); o[5] = f2bf(b.y); o[6] = f2bf(b.z); o[7] = f2bf(b.w);
  *((u16x8*)p.out[z] + i) = o;
}

// ---------------- transpose+cast 1024x1024 f32 weights -> bf16, 4 batched ----
struct T4 { const float* in[4]; u16* out[4]; };
__global__ __launch_bounds__(256) void transpose_w4(T4 p) {
  __shared__ u16 t[64][65];
  const float* in = p.in[blockIdx.z];
  u16* out = p.out[blockIdx.z];
  int r0 = blockIdx.y * 64, c0 = blockIdx.x * 64;
  for (int i = threadIdx.x; i < 4096; i += 256) {
    int r = i >> 6, c = i & 63;
    t[r][c] = f2bf(in[(size_t)(r0 + r) * 1024 + c0 + c]);
  }
  __syncthreads();
  for (int i = threadIdx.x; i < 4096; i += 256) {
    int r = i >> 6, c = i & 63;
    out[(size_t)(c0 + r) * 1024 + r0 + c] = t[c][r];
  }
}

// ---------------- V[B,S,D](bf16) -> VT[b*H+h][64][S] ----------------
__global__ __launch_bounds__(256) void transpose_v(const u16* __restrict__ V,
                                                   u16* __restrict__ VT) {
  __shared__ u16 t[64][65];
  int s0 = blockIdx.x * 64;
  int bh = blockIdx.y, b = bh >> 4, h = bh & 15;
  const u16* src = V + (size_t)b * S_ * D_ + h * 64;
  u16* dst = VT + (size_t)bh * 64 * S_;
  for (int i = threadIdx.x; i < 4096; i += 256) {
    int s = i >> 6, dk = i & 63;
    t[s][dk] = src[(size_t)(s0 + s) * D_ + dk];
  }
  __syncthreads();
  for (int i = threadIdx.x; i < 4096; i += 256) {
    int dk = i >> 6, s = i & 63;
    dst[(size_t)dk * S_ + s0 + s] = t[s][dk];
  }
}

// ---------------- GEMM body: C[M,N] = A[M,K] * BT[N,K]^T (bf16 in) ---------
// Tile 128x64, BK=64, 4 waves (2x2). Verified structure (rounds 2-8).
template <bool OUTF32>
__device__ __forceinline__ void gemm_body(const u16* __restrict__ A,
                                          const u16* __restrict__ BT,
                                          void* __restrict__ Cv) {
  constexpr int K = 1024, N = 1024;
  __shared__ __align__(16) u16 lA[128 * 64];
  __shared__ __align__(16) u16 lB[64 * 64];
  const int tid = threadIdx.x, lane = tid & 63, w = tid >> 6;
  const int wr = w >> 1, wc = w & 1;
  const int m0 = blockIdx.x * 128, n0 = blockIdx.y * 64;
  const int g = lane >> 4, c16 = lane & 15;
  f32x4 acc[4][2] = {};
  const char* Ab = (const char*)(A + (size_t)m0 * K);
  const char* Bb = (const char*)(BT + (size_t)n0 * K);
  char* lAb = (char*)lA;
  char* lBb = (char*)lB;
  for (int kt = 0; kt < K; kt += 64) {
    for (int c = 0; c < 4; ++c) {
      unsigned o = w * 4096 + c * 1024 + lane * 16;
      unsigned u = swz128(o);
      gload_lds16(Ab + (size_t)(u >> 7) * (K * 2) + kt * 2 + (u & 127),
                  lAb + w * 4096 + c * 1024);
    }
    for (int c = 0; c < 2; ++c) {
      unsigned o = w * 2048 + c * 1024 + lane * 16;
      unsigned u = swz128(o);
      gload_lds16(Bb + (size_t)(u >> 7) * (K * 2) + kt * 2 + (u & 127),
                  lBb + w * 2048 + c * 1024);
    }
    asm volatile("s_waitcnt vmcnt(0)" ::: "memory");
    __syncthreads();
    for (int ks = 0; ks < 2; ++ks) {
      bf16x8 af[4], bf[2];
      for (int i = 0; i < 4; ++i) {
        unsigned row = wr * 64 + i * 16 + c16;
        unsigned o = row * 128 + ks * 64 + g * 16;
        af[i] = *(const bf16x8*)(lAb + (o ^ ((row & 7) << 4)));
      }
      for (int j = 0; j < 2; ++j) {
        unsigned row = wc * 32 + j * 16 + c16;
        unsigned o = row * 128 + ks * 64 + g * 16;
        bf[j] = *(const bf16x8*)(lBb + (o ^ ((row & 7) << 4)));
      }
      for (int i = 0; i < 4; ++i)
        for (int j = 0; j < 2; ++j)
          acc[i][j] = __builtin_amdgcn_mfma_f32_16x16x32_bf16(af[i], bf[j],
                                                              acc[i][j], 0, 0, 0);
    }
    __syncthreads();
  }
  for (int i = 0; i < 4; ++i)
    for (int j = 0; j < 2; ++j) {
      int row = m0 + wr * 64 + i * 16 + g * 4;
      int col = n0 + wc * 32 + j * 16 + c16;
      for (int r = 0; r < 4; ++r) {
        if constexpr (OUTF32)
          ((float*)Cv)[(size_t)(row + r) * N + col] = acc[i][j][r];
        else
          ((u16*)Cv)[(size_t)(row + r) * N + col] = f2bf(acc[i][j][r]);
      }
    }
}

struct G3 { const u16* A[3]; const u16* BT[3]; u16* C[3]; };
__global__ __launch_bounds__(256) void gemm_bt3(G3 p) {
  gemm_body<false>(p.A[blockIdx.z], p.BT[blockIdx.z], p.C[blockIdx.z]);
}
__global__ __launch_bounds__(256) void gemm_bt_f32(const u16* __restrict__ A,
                                                   const u16* __restrict__ BT,
                                                   float* __restrict__ C) {
  gemm_body<true>(A, BT, C);
}

// ---------------- flash attention v3 ----------------
// grid (S/64, B*H); 4 waves, wave w owns q rows [w*16, w*16+16).
// Round-7 verified shape + T3 2-phase: double-buffered K/V staging issued
// BEFORE compute, ONE vmcnt(0)+barrier per tile. lQ folded into lP.
__global__ __launch_bounds__(256) void flash_attn(const u16* __restrict__ Q,
                                                  const u16* __restrict__ K,
                                                  const u16* __restrict__ VT,
                                                  u16* __restrict__ O) {
  __shared__ __align__(16) u16 lP[64 * 64];      // Q staging, then P tile
  __shared__ __align__(16) u16 lK[2][64 * 64];   // double-buffered
  __shared__ __align__(16) u16 lV[2][64 * 64];
  const int tid = threadIdx.x, lane = tid & 63, w = tid >> 6;
  const int g = lane >> 4, c16 = lane & 15;
  const int q0 = blockIdx.x * 64;
  const int bh = blockIdx.y, b = bh >> 4, h = bh & 15;
  const char* Qb = (const char*)(Q + (size_t)(b * S_ + q0) * D_ + h * 64);
  const char* Kb = (const char*)(K + (size_t)b * S_ * D_ + h * 64);
  const char* Vb = (const char*)(VT + (size_t)bh * 64 * S_);
  char* lPb = (char*)lP;
  char* lKb = (char*)lK;
  char* lVb = (char*)lV;

  // prologue: Q -> lP (dead after qf load; same-wave rows so reuse is safe),
  // K/V tile 0 -> buffer 0. Sources pre-swizzled (rule #21), dests linear.
  for (int c = 0; c < 2; ++c) {
    unsigned o = w * 2048 + c * 1024 + lane * 16;
    unsigned u = swz128(o);
    gload_lds16(Qb + (size_t)(u >> 7) * (D_ * 2) + (u & 127), lPb + w * 2048 + c * 1024);
    gload_lds16(Kb + (size_t)(u >> 7) * (D_ * 2) + (u & 127), lKb + w * 2048 + c * 1024);
    gload_lds16(Vb + (size_t)(u >> 7) * (S_ * 2) + (u & 127), lVb + w * 2048 + c * 1024);
  }
  float m_run[4], l_run[4];
  f32x4 oacc[4] = {};
  for (int r = 0; r < 4; ++r) { m_run[r] = -INFINITY; l_run[r] = 0.f; }
  asm volatile("s_waitcnt vmcnt(0)" ::: "memory");
  __syncthreads();
  bf16x8 qf[2];
  {
    unsigned row = w * 16 + c16;
    for (int ks = 0; ks < 2; ++ks) {
      unsigned o = row * 128 + ks * 64 + g * 16;
      qf[ks] = *(const bf16x8*)(lPb + swz128(o));
    }
  }
  const float SC2 = 0.125f * 1.44269504088896340736f;  // SCALE * log2(e)
  int cur = 0;
  for (int kv0 = 0; kv0 < S_; kv0 += 64, cur ^= 1) {
    char* curK = lKb + cur * 8192;
    char* curV = lVb + cur * 8192;
    // T3: issue next tile's staging BEFORE compute; in flight across compute.
    if (kv0 + 64 < S_) {
      char* nK = lKb + (cur ^ 1) * 8192;
      char* nV = lVb + (cur ^ 1) * 8192;
      for (int c = 0; c < 2; ++c) {
        unsigned o = w * 2048 + c * 1024 + lane * 16;
        unsigned u = swz128(o);
        gload_lds16(Kb + (size_t)(kv0 + 64 + (u >> 7)) * (D_ * 2) + (u & 127),
                    nK + w * 2048 + c * 1024);
        gload_lds16(Vb + (size_t)(u >> 7) * (S_ * 2) + (size_t)(kv0 + 64) * 2 + (u & 127),
                    nV + w * 2048 + c * 1024);
      }
    }
    // S = Q K^T
    f32x4 s[4] = {};
    for (int ks = 0; ks < 2; ++ks)
      for (int j = 0; j < 4; ++j) {
        unsigned row = j * 16 + c16;
        unsigned o = row * 128 + ks * 64 + g * 16;
        bf16x8 kf = *(const bf16x8*)(curK + swz128(o));
        s[j] = __builtin_amdgcn_mfma_f32_16x16x32_bf16(qf[ks], kf, s[j], 0, 0, 0);
      }
    // online softmax; lane holds q=w*16+g*4+r, kv=j*16+c16
    for (int r = 0; r < 4; ++r) {
      float rm = fmaxf(fmaxf(s[0][r], s[1][r]), fmaxf(s[2][r], s[3][r]));
      rm = fmaxf(rm, __shfl_xor(rm, 1));
      rm = fmaxf(rm, __shfl_xor(rm, 2));
      rm = fmaxf(rm, __shfl_xor(rm, 4));
      rm = fmaxf(rm, __shfl_xor(rm, 8));
      float mn = fmaxf(m_run[r], rm);
      float sc = exp2f((m_run[r] - mn) * SC2);
      m_run[r] = mn;
      float p[4], rs = 0.f;
      for (int j = 0; j < 4; ++j) {
        p[j] = exp2f((s[j][r] - mn) * SC2);
        rs += p[j];
      }
      rs += __shfl_xor(rs, 1);
      rs += __shfl_xor(rs, 2);
      rs += __shfl_xor(rs, 4);
      rs += __shfl_xor(rs, 8);
      l_run[r] = l_run[r] * sc + rs;
      for (int j = 0; j < 4; ++j) oacc[j][r] *= sc;
      unsigned qrow = w * 16 + g * 4 + r;
      for (int j = 0; j < 4; ++j) {
        unsigned o = qrow * 128 + (unsigned)(j * 16 + c16) * 2;
        *(u16*)(lPb + swz128(o)) = f2bf(p[j]);
      }
    }
    // O += P V. P rows are wave-private (written & read by wave w only);
    // same-wave ds ordering via lgkmcnt — no barrier needed here.
    {
      unsigned prow = w * 16 + c16;
      for (int ks = 0; ks < 2; ++ks) {
        unsigned po = prow * 128 + ks * 64 + g * 16;
        bf16x8 pf = *(const bf16x8*)(lPb + swz128(po));
        for (int j = 0; j < 4; ++j) {
          unsigned vrow = j * 16 + c16;
          unsigned vo = vrow * 128 + ks * 64 + g * 16;
          bf16x8 vf = *(const bf16x8*)(curV + swz128(vo));
          oacc[j] = __builtin_amdgcn_mfma_f32_16x16x32_bf16(pf, vf, oacc[j], 0, 0, 0);
        }
      }
    }
    // single drain+barrier per tile: staged writes landed AND all waves done
    // reading buffer `cur` before it is overwritten next iteration.
    asm volatile("s_waitcnt vmcnt(0)" ::: "memory");
    __syncthreads();
  }
  for (int j = 0; j < 4; ++j)
    for (int r = 0; r < 4; ++r) {
      int q = q0 + w * 16 + g * 4 + r;
      int col = h * 64 + j * 16 + c16;
      O[(size_t)(b * S_ + q) * D_ + col] = f2bf(oacc[j][r] / l_run[r]);
    }
}

extern "C" void kernel_launch(void* const* d_in, const int* in_sizes, int n_in,
                              void* d_out, int out_size, void* d_ws, size_t ws_size,
                              hipStream_t stream) {
  const float* q_in = (const float*)d_in[0];
  const float* k_in = (const float*)d_in[1];
  const float* v_in = (const float*)d_in[2];
  const float* Wq = (const float*)d_in[3];
  const float* Wk = (const float*)d_in[4];
  const float* Wv = (const float*)d_in[5];
  const float* Wo = (const float*)d_in[6];
  u16* ws = (u16*)d_ws;
  const size_t WSZ = (size_t)1024 * 1024;
  const size_t TSZ = (size_t)B_ * S_ * D_;  // 4,194,304
  u16* WqT = ws;
  u16* WkT = ws + WSZ;
  u16* WvT = ws + 2 * WSZ;
  u16* WoT = ws + 3 * WSZ;
  u16* Qc = ws + 4 * WSZ;   // casted bf16 inputs
  u16* Kc = Qc + TSZ;
  u16* Vc = Kc + TSZ;
  u16* Qb = Vc + TSZ;       // projected
  u16* Kb = Qb + TSZ;
  u16* Vb = Kb + TSZ;
  u16* VTb = Kc;            // alias: Kc dead after K projection
  u16* Ob = Qc;             // alias: Qc dead after Q projection
  dim3 tb(256);
  T4 tw = {{Wq, Wk, Wv, Wo}, {WqT, WkT, WvT, WoT}};
  transpose_w4<<<dim3(16, 16, 4), tb, 0, stream>>>(tw);
  int n8 = (int)(TSZ / 8);
  C3 cc = {{q_in, k_in, v_in}, {Qc, Kc, Vc}};
  cast3<<<dim3(n8 / 256, 3), tb, 0, stream>>>(cc, n8);
  G3 gg = {{Qc, Kc, Vc}, {WqT, WkT, WvT}, {Qb, Kb, Vb}};
  gemm_bt3<<<dim3(32, 16, 3), tb, 0, stream>>>(gg);
  transpose_v<<<dim3(32, 32), tb, 0, stream>>>(Vb, VTb);
  flash_attn<<<dim3(S_ / 64, B_ * H_), tb, 0, stream>>>(Qb, Kb, VTb, Ob);
  gemm_bt_f32<<<dim3(32, 16), tb, 0, stream>>>(Ob, WoT, (float*)d_out);
}

// Round 10
// 179.504 us; speedup vs baseline: 1.9527x; 1.1723x over previous
//
#include <hip/hip_runtime.h>

#define B_ 2
#define S_ 2048
#define D_ 1024
#define H_ 16

typedef unsigned short u16;
typedef __bf16 bf16x8 __attribute__((ext_vector_type(8)));
typedef float f32x4 __attribute__((ext_vector_type(4)));
typedef unsigned short u16x8 __attribute__((ext_vector_type(8)));
typedef unsigned short u16x4 __attribute__((ext_vector_type(4)));

__device__ __forceinline__ unsigned swz128(unsigned o) {  // 128B rows
  return o ^ (((o >> 7) & 7) << 4);
}

__device__ __forceinline__ void gload_lds16(const void* g, void* l) {
  __builtin_amdgcn_global_load_lds(
      (const __attribute__((address_space(1))) unsigned*)g,
      (__attribute__((address_space(3))) unsigned*)l, 16, 0, 0);
}

__device__ __forceinline__ u16 f2bf(float f) {
  union { float f; unsigned u; } v;
  v.f = f;
  unsigned u = v.u;
  return (u16)((u + 0x7fffu + ((u >> 16) & 1u)) >> 16);
}

// ---------------- f32 -> bf16 cast, 3 tensors batched ----------------
struct C3 { const float* in[3]; u16* out[3]; };
__global__ __launch_bounds__(256) void cast3(C3 p, int n8) {
  int z = blockIdx.y;
  int i = blockIdx.x * 256 + threadIdx.x;
  if (i >= n8) return;
  const float4* src = (const float4*)p.in[z] + (size_t)i * 2;
  float4 a = src[0], b = src[1];
  u16x8 o;
  o[0] = f2bf(a.x); o[1] = f2bf(a.y); o[2] = f2bf(a.z); o[3] = f2bf(a.w);
  o[4] = f2bf(b.x); o[5] = f2bf(b.y); o[6] = f2bf(b.z); o[7] = f2bf(b.w);
  *((u16x8*)p.out[z] + i) = o;
}

// ---------------- transpose+cast 1024x1024 f32 weights -> bf16, 4 batched ----
struct T4 { const float* in[4]; u16* out[4]; };
__global__ __launch_bounds__(256) void transpose_w4(T4 p) {
  __shared__ u16 t[64][65];
  const float* in = p.in[blockIdx.z];
  u16* out = p.out[blockIdx.z];
  int r0 = blockIdx.y * 64, c0 = blockIdx.x * 64;
  for (int i = threadIdx.x; i < 4096; i += 256) {
    int r = i >> 6, c = i & 63;
    t[r][c] = f2bf(in[(size_t)(r0 + r) * 1024 + c0 + c]);
  }
  __syncthreads();
  for (int i = threadIdx.x; i < 4096; i += 256) {
    int r = i >> 6, c = i & 63;
    out[(size_t)(c0 + r) * 1024 + r0 + c] = t[c][r];
  }
}

// ---------------- V[B,S,D](bf16) -> VT[b*H+h][64][S] ----------------
__global__ __launch_bounds__(256) void transpose_v(const u16* __restrict__ V,
                                                   u16* __restrict__ VT) {
  __shared__ u16 t[64][65];
  int s0 = blockIdx.x * 64;
  int bh = blockIdx.y, b = bh >> 4, h = bh & 15;
  const u16* src = V + (size_t)b * S_ * D_ + h * 64;
  u16* dst = VT + (size_t)bh * 64 * S_;
  for (int i = threadIdx.x; i < 4096; i += 256) {
    int s = i >> 6, dk = i & 63;
    t[s][dk] = src[(size_t)(s0 + s) * D_ + dk];
  }
  __syncthreads();
  for (int i = threadIdx.x; i < 4096; i += 256) {
    int dk = i >> 6, s = i & 63;
    dst[(size_t)dk * S_ + s0 + s] = t[s][dk];
  }
}

// ---------------- GEMM body: C[M,N] = A[M,K] * BT[N,K]^T (bf16 in) ---------
// Tile 128x64, BK=64, 4 waves (2x2). Verified structure (rounds 2-9).
template <bool OUTF32>
__device__ __forceinline__ void gemm_body(const u16* __restrict__ A,
                                          const u16* __restrict__ BT,
                                          void* __restrict__ Cv) {
  constexpr int K = 1024, N = 1024;
  __shared__ __align__(16) u16 lA[128 * 64];
  __shared__ __align__(16) u16 lB[64 * 64];
  const int tid = threadIdx.x, lane = tid & 63, w = tid >> 6;
  const int wr = w >> 1, wc = w & 1;
  const int m0 = blockIdx.x * 128, n0 = blockIdx.y * 64;
  const int g = lane >> 4, c16 = lane & 15;
  f32x4 acc[4][2] = {};
  const char* Ab = (const char*)(A + (size_t)m0 * K);
  const char* Bb = (const char*)(BT + (size_t)n0 * K);
  char* lAb = (char*)lA;
  char* lBb = (char*)lB;
  for (int kt = 0; kt < K; kt += 64) {
    for (int c = 0; c < 4; ++c) {
      unsigned o = w * 4096 + c * 1024 + lane * 16;
      unsigned u = swz128(o);
      gload_lds16(Ab + (size_t)(u >> 7) * (K * 2) + kt * 2 + (u & 127),
                  lAb + w * 4096 + c * 1024);
    }
    for (int c = 0; c < 2; ++c) {
      unsigned o = w * 2048 + c * 1024 + lane * 16;
      unsigned u = swz128(o);
      gload_lds16(Bb + (size_t)(u >> 7) * (K * 2) + kt * 2 + (u & 127),
                  lBb + w * 2048 + c * 1024);
    }
    asm volatile("s_waitcnt vmcnt(0)" ::: "memory");
    __syncthreads();
    for (int ks = 0; ks < 2; ++ks) {
      bf16x8 af[4], bf[2];
      for (int i = 0; i < 4; ++i) {
        unsigned row = wr * 64 + i * 16 + c16;
        unsigned o = row * 128 + ks * 64 + g * 16;
        af[i] = *(const bf16x8*)(lAb + (o ^ ((row & 7) << 4)));
      }
      for (int j = 0; j < 2; ++j) {
        unsigned row = wc * 32 + j * 16 + c16;
        unsigned o = row * 128 + ks * 64 + g * 16;
        bf[j] = *(const bf16x8*)(lBb + (o ^ ((row & 7) << 4)));
      }
      for (int i = 0; i < 4; ++i)
        for (int j = 0; j < 2; ++j)
          acc[i][j] = __builtin_amdgcn_mfma_f32_16x16x32_bf16(af[i], bf[j],
                                                              acc[i][j], 0, 0, 0);
    }
    __syncthreads();
  }
  for (int i = 0; i < 4; ++i)
    for (int j = 0; j < 2; ++j) {
      int row = m0 + wr * 64 + i * 16 + g * 4;
      int col = n0 + wc * 32 + j * 16 + c16;
      for (int r = 0; r < 4; ++r) {
        if constexpr (OUTF32)
          ((float*)Cv)[(size_t)(row + r) * N + col] = acc[i][j][r];
        else
          ((u16*)Cv)[(size_t)(row + r) * N + col] = f2bf(acc[i][j][r]);
      }
    }
}

struct G3 { const u16* A[3]; const u16* BT[3]; u16* C[3]; };
__global__ __launch_bounds__(256) void gemm_bt3(G3 p) {
  gemm_body<false>(p.A[blockIdx.z], p.BT[blockIdx.z], p.C[blockIdx.z]);
}
__global__ __launch_bounds__(256) void gemm_bt_f32(const u16* __restrict__ A,
                                                   const u16* __restrict__ BT,
                                                   float* __restrict__ C) {
  gemm_body<true>(A, BT, C);
}

// ---------------- flash attention v4: swapped QK^T, in-register softmax ----
// grid (S/64, B*H); 4 waves, wave w owns q rows [w*16, w*16+16).
// S^T = mfma(K,Q): lane owns ONE q-row (q=w*16+c16), 16 kv-scores in regs
// (kv = j*16+g*4+r). Row reduce = in-reg + 2 shuffles. PV: O^T = mfma(VT,P).
__global__ __launch_bounds__(256) void flash_attn(const u16* __restrict__ Q,
                                                  const u16* __restrict__ K,
                                                  const u16* __restrict__ VT,
                                                  u16* __restrict__ O) {
  __shared__ __align__(16) u16 lP[64 * 64];      // Q staging, then P tile
  __shared__ __align__(16) u16 lK[2][64 * 64];   // double-buffered
  __shared__ __align__(16) u16 lV[2][64 * 64];
  const int tid = threadIdx.x, lane = tid & 63, w = tid >> 6;
  const int g = lane >> 4, c16 = lane & 15;
  const int q0 = blockIdx.x * 64;
  const int bh = blockIdx.y, b = bh >> 4, h = bh & 15;
  const char* Qb = (const char*)(Q + (size_t)(b * S_ + q0) * D_ + h * 64);
  const char* Kb = (const char*)(K + (size_t)b * S_ * D_ + h * 64);
  const char* Vb = (const char*)(VT + (size_t)bh * 64 * S_);
  char* lPb = (char*)lP;
  char* lKb = (char*)lK;
  char* lVb = (char*)lV;

  // prologue: Q -> lP (dead after qf load), K/V tile 0 -> buffer 0.
  for (int c = 0; c < 2; ++c) {
    unsigned o = w * 2048 + c * 1024 + lane * 16;
    unsigned u = swz128(o);
    gload_lds16(Qb + (size_t)(u >> 7) * (D_ * 2) + (u & 127), lPb + w * 2048 + c * 1024);
    gload_lds16(Kb + (size_t)(u >> 7) * (D_ * 2) + (u & 127), lKb + w * 2048 + c * 1024);
    gload_lds16(Vb + (size_t)(u >> 7) * (S_ * 2) + (u & 127), lVb + w * 2048 + c * 1024);
  }
  float m_run = -INFINITY, l_run = 0.f;
  f32x4 oacc[4] = {};  // oacc[i][r] = O^T[dk=i*16+g*4+r][q=w*16+c16]
  asm volatile("s_waitcnt vmcnt(0)" ::: "memory");
  __syncthreads();
  bf16x8 qf[2];
  {
    unsigned row = w * 16 + c16;
    for (int ks = 0; ks < 2; ++ks) {
      unsigned o = row * 128 + ks * 64 + g * 16;
      qf[ks] = *(const bf16x8*)(lPb + swz128(o));
    }
  }
  const float SC2 = 0.125f * 1.44269504088896340736f;  // SCALE * log2(e)
  int cur = 0;
  for (int kv0 = 0; kv0 < S_; kv0 += 64, cur ^= 1) {
    char* curK = lKb + cur * 8192;
    char* curV = lVb + cur * 8192;
    // T3: issue next tile's staging BEFORE compute.
    if (kv0 + 64 < S_) {
      char* nK = lKb + (cur ^ 1) * 8192;
      char* nV = lVb + (cur ^ 1) * 8192;
      for (int c = 0; c < 2; ++c) {
        unsigned o = w * 2048 + c * 1024 + lane * 16;
        unsigned u = swz128(o);
        gload_lds16(Kb + (size_t)(kv0 + 64 + (u >> 7)) * (D_ * 2) + (u & 127),
                    nK + w * 2048 + c * 1024);
        gload_lds16(Vb + (size_t)(u >> 7) * (S_ * 2) + (size_t)(kv0 + 64) * 2 + (u & 127),
                    nV + w * 2048 + c * 1024);
      }
    }
    // S^T = K Q^T: s[j][r] = S[kv=j*16+g*4+r][q=w*16+c16] (raw scores)
    f32x4 s[4] = {};
    for (int ks = 0; ks < 2; ++ks)
      for (int j = 0; j < 4; ++j) {
        unsigned row = j * 16 + c16;
        unsigned o = row * 128 + ks * 64 + g * 16;
        bf16x8 kf = *(const bf16x8*)(curK + swz128(o));
        s[j] = __builtin_amdgcn_mfma_f32_16x16x32_bf16(kf, qf[ks], s[j], 0, 0, 0);
      }
    // in-register softmax for this lane's single q-row
    float rm = s[0][0];
    for (int j = 0; j < 4; ++j)
      for (int r = 0; r < 4; ++r) rm = fmaxf(rm, s[j][r]);
    rm = fmaxf(rm, __shfl_xor(rm, 16));
    rm = fmaxf(rm, __shfl_xor(rm, 32));
    // T13 defer-rescale: skip O-rescale while tile max stays within 8/SC2.
    if (!__all((rm - m_run) * SC2 <= 8.0f)) {
      float mn = fmaxf(m_run, rm);
      float sc = exp2f((m_run - mn) * SC2);
      l_run *= sc;
      for (int i = 0; i < 4; ++i) oacc[i] *= sc;
      m_run = mn;
    }
    float rs = 0.f;
    unsigned qrow = w * 16 + c16;
    for (int j = 0; j < 4; ++j) {
      float p0 = exp2f((s[j][0] - m_run) * SC2);
      float p1 = exp2f((s[j][1] - m_run) * SC2);
      float p2 = exp2f((s[j][2] - m_run) * SC2);
      float p3 = exp2f((s[j][3] - m_run) * SC2);
      rs += (p0 + p1) + (p2 + p3);
      unsigned w0 = (unsigned)f2bf(p0) | ((unsigned)f2bf(p1) << 16);
      unsigned w1 = (unsigned)f2bf(p2) | ((unsigned)f2bf(p3) << 16);
      unsigned o = qrow * 128 + (unsigned)(j * 16 + g * 4) * 2;
      unsigned so = swz128(o);
      *(unsigned*)(lPb + so) = w0;
      *(unsigned*)(lPb + so + 4) = w1;
    }
    rs += __shfl_xor(rs, 16);
    rs += __shfl_xor(rs, 32);
    l_run += rs;
    // O^T += V^T P: A=V^T-frag (rows dk), B=P-frag (rows q, wave-private)
    for (int ks = 0; ks < 2; ++ks) {
      unsigned po = qrow * 128 + ks * 64 + g * 16;
      bf16x8 pf = *(const bf16x8*)(lPb + swz128(po));
      for (int i = 0; i < 4; ++i) {
        unsigned vo = (unsigned)(i * 16 + c16) * 128 + ks * 64 + g * 16;
        bf16x8 vf = *(const bf16x8*)(curV + swz128(vo));
        oacc[i] = __builtin_amdgcn_mfma_f32_16x16x32_bf16(vf, pf, oacc[i], 0, 0, 0);
      }
    }
    asm volatile("s_waitcnt vmcnt(0)" ::: "memory");
    __syncthreads();
  }
  // epilogue: lane holds O^T[dk=i*16+g*4+r][q=w*16+c16]
  float inv = 1.f / l_run;
  int q = q0 + w * 16 + c16;
  u16* orow = O + (size_t)(b * S_ + q) * D_ + h * 64;
  for (int i = 0; i < 4; ++i) {
    u16x4 ov;
    for (int r = 0; r < 4; ++r) ov[r] = f2bf(oacc[i][r] * inv);
    *(u16x4*)(orow + i * 16 + g * 4) = ov;
  }
}

extern "C" void kernel_launch(void* const* d_in, const int* in_sizes, int n_in,
                              void* d_out, int out_size, void* d_ws, size_t ws_size,
                              hipStream_t stream) {
  const float* q_in = (const float*)d_in[0];
  const float* k_in = (const float*)d_in[1];
  const float* v_in = (const float*)d_in[2];
  const float* Wq = (const float*)d_in[3];
  const float* Wk = (const float*)d_in[4];
  const float* Wv = (const float*)d_in[5];
  const float* Wo = (const float*)d_in[6];
  u16* ws = (u16*)d_ws;
  const size_t WSZ = (size_t)1024 * 1024;
  const size_t TSZ = (size_t)B_ * S_ * D_;  // 4,194,304
  u16* WqT = ws;
  u16* WkT = ws + WSZ;
  u16* WvT = ws + 2 * WSZ;
  u16* WoT = ws + 3 * WSZ;
  u16* Qc = ws + 4 * WSZ;   // casted bf16 inputs
  u16* Kc = Qc + TSZ;
  u16* Vc = Kc + TSZ;
  u16* Qb = Vc + TSZ;       // projected
  u16* Kb = Qb + TSZ;
  u16* Vb = Kb + TSZ;
  u16* VTb = Kc;            // alias: Kc dead after K projection
  u16* Ob = Qc;             // alias: Qc dead after Q projection
  dim3 tb(256);
  T4 tw = {{Wq, Wk, Wv, Wo}, {WqT, WkT, WvT, WoT}};
  transpose_w4<<<dim3(16, 16, 4), tb, 0, stream>>>(tw);
  int n8 = (int)(TSZ / 8);
  C3 cc = {{q_in, k_in, v_in}, {Qc, Kc, Vc}};
  cast3<<<dim3(n8 / 256, 3), tb, 0, stream>>>(cc, n8);
  G3 gg = {{Qc, Kc, Vc}, {WqT, WkT, WvT}, {Qb, Kb, Vb}};
  gemm_bt3<<<dim3(32, 16, 3), tb, 0, stream>>>(gg);
  transpose_v<<<dim3(32, 32), tb, 0, stream>>>(Vb, VTb);
  flash_attn<<<dim3(S_ / 64, B_ * H_), tb, 0, stream>>>(Qb, Kb, VTb, Ob);
  gemm_bt_f32<<<dim3(32, 16), tb, 0, stream>>>(Ob, WoT, (float*)d_out);
}

// Round 11
// 168.145 us; speedup vs baseline: 2.0846x; 1.0676x over previous
//
#include <hip/hip_runtime.h>

#define B_ 2
#define S_ 2048
#define D_ 1024
#define H_ 16

typedef unsigned short u16;
typedef unsigned long long u64;
typedef __bf16 bf16x8 __attribute__((ext_vector_type(8)));
typedef float f32x4 __attribute__((ext_vector_type(4)));
typedef unsigned short u16x8 __attribute__((ext_vector_type(8)));
typedef unsigned uint4v __attribute__((ext_vector_type(4)));

__device__ __forceinline__ unsigned swz128(unsigned o) {  // 128B rows
  return o ^ (((o >> 7) & 7) << 4);
}

__device__ __forceinline__ void gload_lds16(const void* g, void* l) {
  __builtin_amdgcn_global_load_lds(
      (const __attribute__((address_space(1))) unsigned*)g,
      (__attribute__((address_space(3))) unsigned*)l, 16, 0, 0);
}

__device__ __forceinline__ u16 f2bf(float f) {
  union { float f; unsigned u; } v;
  v.f = f;
  unsigned u = v.u;
  return (u16)((u + 0x7fffu + ((u >> 16) & 1u)) >> 16);
}

// RNE pack of two f32 -> one dword of 2 bf16 (lo,hi). gfx950 HW instruction.
__device__ __forceinline__ unsigned cvtpk(float lo, float hi) {
  unsigned d;
  asm("v_cvt_pk_bf16_f32 %0, %1, %2" : "=v"(d) : "v"(lo), "v"(hi));
  return d;
}

// ---------------- transpose+cast 1024x1024 f32 weights -> bf16, 4 batched ----
struct T4 { const float* in[4]; u16* out[4]; };
__global__ __launch_bounds__(256) void transpose_w4(T4 p) {
  __shared__ u16 t[64][65];
  const float* in = p.in[blockIdx.z];
  u16* out = p.out[blockIdx.z];
  int r0 = blockIdx.y * 64, c0 = blockIdx.x * 64;
  for (int i = threadIdx.x; i < 4096; i += 256) {
    int r = i >> 6, c = i & 63;
    t[r][c] = f2bf(in[(size_t)(r0 + r) * 1024 + c0 + c]);
  }
  __syncthreads();
  for (int i = threadIdx.x; i < 4096; i += 256) {
    int r = i >> 6, c = i & 63;
    out[(size_t)(c0 + r) * 1024 + r0 + c] = t[c][r];
  }
}

// ---------------- V[B,S,D](bf16) -> VT[b*H+h][64][S] ----------------
__global__ __launch_bounds__(256) void transpose_v(const u16* __restrict__ V,
                                                   u16* __restrict__ VT) {
  __shared__ u16 t[64][65];
  int s0 = blockIdx.x * 64;
  int bh = blockIdx.y, b = bh >> 4, h = bh & 15;
  const u16* src = V + (size_t)b * S_ * D_ + h * 64;
  u16* dst = VT + (size_t)bh * 64 * S_;
  for (int i = threadIdx.x; i < 4096; i += 256) {
    int s = i >> 6, dk = i & 63;
    t[s][dk] = src[(size_t)(s0 + s) * D_ + dk];
  }
  __syncthreads();
  for (int i = threadIdx.x; i < 4096; i += 256) {
    int dk = i >> 6, s = i & 63;
    dst[(size_t)dk * S_ + s0 + s] = t[s][dk];
  }
}

// ---------------- fused cast+GEMM (m97 128x128 structure) ------------------
// C[M,N] = bf16(A_f32)[M,K] @ BT[N,K]^T. A reg-staged f32->bf16 via cvt_pk
// (swizzled ds_write); B via global_load_lds w16 (pre-swizzled source).
// 4 waves 2x2, each 64x64 out (4x4 frags). Grid (M/128, N/128, 3).
struct QKV { const float* A[3]; const u16* BT[3]; u16* C[3]; };
__global__ __launch_bounds__(256) void gemm_qkv(QKV p) {
  constexpr int K = 1024, N = 1024;
  __shared__ __align__(16) u16 lA[128 * 64];
  __shared__ __align__(16) u16 lB[128 * 64];
  const int tid = threadIdx.x, lane = tid & 63, w = tid >> 6;
  const int wr = w >> 1, wc = w & 1;
  const int m0 = blockIdx.x * 128, n0 = blockIdx.y * 128;
  const int g = lane >> 4, c16 = lane & 15;
  const int z = blockIdx.z;
  f32x4 acc[4][4] = {};
  const float* Af = p.A[z] + (size_t)m0 * K;
  const char* Bb = (const char*)(p.BT[z] + (size_t)n0 * K);
  u16* C = p.C[z];
  char* lAb = (char*)lA;
  char* lBb = (char*)lB;
  for (int kt = 0; kt < K; kt += 64) {
    // B tile 128x64 (16KB): async gload, linear dest, pre-swizzled source.
    for (int c = 0; c < 4; ++c) {
      unsigned o = c * 4096 + tid * 16;
      unsigned u = swz128(o);
      gload_lds16(Bb + (size_t)(u >> 7) * (K * 2) + kt * 2 + (u & 127), lBb + o);
    }
    // A tile 128x64 f32 -> bf16 (16KB out): reg-staged, swizzled dest.
    for (int c = 0; c < 4; ++c) {
      unsigned o = c * 4096 + tid * 16;       // linear bf16 byte offset
      unsigned row = o >> 7, kc = (o & 127) >> 1;
      const float* s = Af + (size_t)row * K + kt + kc;
      float4 f0 = *(const float4*)s;
      float4 f1 = *(const float4*)(s + 4);
      uint4v d;
      d[0] = cvtpk(f0.x, f0.y);
      d[1] = cvtpk(f0.z, f0.w);
      d[2] = cvtpk(f1.x, f1.y);
      d[3] = cvtpk(f1.z, f1.w);
      *(uint4v*)(lAb + swz128(o)) = d;
    }
    asm volatile("s_waitcnt vmcnt(0)" ::: "memory");
    __syncthreads();
    for (int ks = 0; ks < 2; ++ks) {
      bf16x8 af[4], bf[4];
      for (int i = 0; i < 4; ++i) {
        unsigned row = wr * 64 + i * 16 + c16;
        unsigned o = row * 128 + ks * 64 + g * 16;
        af[i] = *(const bf16x8*)(lAb + (o ^ ((row & 7) << 4)));
      }
      for (int j = 0; j < 4; ++j) {
        unsigned row = wc * 64 + j * 16 + c16;
        unsigned o = row * 128 + ks * 64 + g * 16;
        bf[j] = *(const bf16x8*)(lBb + (o ^ ((row & 7) << 4)));
      }
      for (int i = 0; i < 4; ++i)
        for (int j = 0; j < 4; ++j)
          acc[i][j] = __builtin_amdgcn_mfma_f32_16x16x32_bf16(af[i], bf[j],
                                                              acc[i][j], 0, 0, 0);
    }
    __syncthreads();
  }
  for (int i = 0; i < 4; ++i)
    for (int j = 0; j < 4; ++j) {
      int row = m0 + wr * 64 + i * 16 + g * 4;
      int col = n0 + wc * 64 + j * 16 + c16;
      for (int r = 0; r < 4; ++r)
        C[(size_t)(row + r) * N + col] = f2bf(acc[i][j][r]);
    }
}

// ---------------- GEMM body (bf16 A): final projection, f32 out ------------
// Tile 128x64, BK=64, 4 waves (2x2). Verified structure (rounds 2-10).
__global__ __launch_bounds__(256) void gemm_bt_f32(const u16* __restrict__ A,
                                                   const u16* __restrict__ BT,
                                                   float* __restrict__ C) {
  constexpr int K = 1024, N = 1024;
  __shared__ __align__(16) u16 lA[128 * 64];
  __shared__ __align__(16) u16 lB[64 * 64];
  const int tid = threadIdx.x, lane = tid & 63, w = tid >> 6;
  const int wr = w >> 1, wc = w & 1;
  const int m0 = blockIdx.x * 128, n0 = blockIdx.y * 64;
  const int g = lane >> 4, c16 = lane & 15;
  f32x4 acc[4][2] = {};
  const char* Ab = (const char*)(A + (size_t)m0 * K);
  const char* Bb = (const char*)(BT + (size_t)n0 * K);
  char* lAb = (char*)lA;
  char* lBb = (char*)lB;
  for (int kt = 0; kt < K; kt += 64) {
    for (int c = 0; c < 4; ++c) {
      unsigned o = w * 4096 + c * 1024 + lane * 16;
      unsigned u = swz128(o);
      gload_lds16(Ab + (size_t)(u >> 7) * (K * 2) + kt * 2 + (u & 127),
                  lAb + w * 4096 + c * 1024);
    }
    for (int c = 0; c < 2; ++c) {
      unsigned o = w * 2048 + c * 1024 + lane * 16;
      unsigned u = swz128(o);
      gload_lds16(Bb + (size_t)(u >> 7) * (K * 2) + kt * 2 + (u & 127),
                  lBb + w * 2048 + c * 1024);
    }
    asm volatile("s_waitcnt vmcnt(0)" ::: "memory");
    __syncthreads();
    for (int ks = 0; ks < 2; ++ks) {
      bf16x8 af[4], bf[2];
      for (int i = 0; i < 4; ++i) {
        unsigned row = wr * 64 + i * 16 + c16;
        unsigned o = row * 128 + ks * 64 + g * 16;
        af[i] = *(const bf16x8*)(lAb + (o ^ ((row & 7) << 4)));
      }
      for (int j = 0; j < 2; ++j) {
        unsigned row = wc * 32 + j * 16 + c16;
        unsigned o = row * 128 + ks * 64 + g * 16;
        bf[j] = *(const bf16x8*)(lBb + (o ^ ((row & 7) << 4)));
      }
      for (int i = 0; i < 4; ++i)
        for (int j = 0; j < 2; ++j)
          acc[i][j] = __builtin_amdgcn_mfma_f32_16x16x32_bf16(af[i], bf[j],
                                                              acc[i][j], 0, 0, 0);
    }
    __syncthreads();
  }
  for (int i = 0; i < 4; ++i)
    for (int j = 0; j < 2; ++j) {
      int row = m0 + wr * 64 + i * 16 + g * 4;
      int col = n0 + wc * 32 + j * 16 + c16;
      for (int r = 0; r < 4; ++r)
        C[(size_t)(row + r) * N + col] = acc[i][j][r];
    }
}

// ---------------- flash attention v5: swapped QK^T + cvt_pk P-pack ---------
// grid (S/64, B*H); 4 waves, wave w owns q rows [w*16, w*16+16).
// S^T = mfma(K,Q): lane owns ONE q-row (q=w*16+c16), 16 kv-scores in regs.
__global__ __launch_bounds__(256) void flash_attn(const u16* __restrict__ Q,
                                                  const u16* __restrict__ K,
                                                  const u16* __restrict__ VT,
                                                  u16* __restrict__ O) {
  __shared__ __align__(16) u16 lP[64 * 64];      // Q staging, then P tile
  __shared__ __align__(16) u16 lK[2][64 * 64];   // double-buffered
  __shared__ __align__(16) u16 lV[2][64 * 64];
  const int tid = threadIdx.x, lane = tid & 63, w = tid >> 6;
  const int g = lane >> 4, c16 = lane & 15;
  const int q0 = blockIdx.x * 64;
  const int bh = blockIdx.y, b = bh >> 4, h = bh & 15;
  const char* Qb = (const char*)(Q + (size_t)(b * S_ + q0) * D_ + h * 64);
  const char* Kb = (const char*)(K + (size_t)b * S_ * D_ + h * 64);
  const char* Vb = (const char*)(VT + (size_t)bh * 64 * S_);
  char* lPb = (char*)lP;
  char* lKb = (char*)lK;
  char* lVb = (char*)lV;

  for (int c = 0; c < 2; ++c) {
    unsigned o = w * 2048 + c * 1024 + lane * 16;
    unsigned u = swz128(o);
    gload_lds16(Qb + (size_t)(u >> 7) * (D_ * 2) + (u & 127), lPb + w * 2048 + c * 1024);
    gload_lds16(Kb + (size_t)(u >> 7) * (D_ * 2) + (u & 127), lKb + w * 2048 + c * 1024);
    gload_lds16(Vb + (size_t)(u >> 7) * (S_ * 2) + (u & 127), lVb + w * 2048 + c * 1024);
  }
  float m_run = -INFINITY, l_run = 0.f;
  f32x4 oacc[4] = {};  // oacc[i][r] = O^T[dk=i*16+g*4+r][q=w*16+c16]
  asm volatile("s_waitcnt vmcnt(0)" ::: "memory");
  __syncthreads();
  bf16x8 qf[2];
  {
    unsigned row = w * 16 + c16;
    for (int ks = 0; ks < 2; ++ks) {
      unsigned o = row * 128 + ks * 64 + g * 16;
      qf[ks] = *(const bf16x8*)(lPb + swz128(o));
    }
  }
  const float SC2 = 0.125f * 1.44269504088896340736f;  // SCALE * log2(e)
  int cur = 0;
  for (int kv0 = 0; kv0 < S_; kv0 += 64, cur ^= 1) {
    char* curK = lKb + cur * 8192;
    char* curV = lVb + cur * 8192;
    if (kv0 + 64 < S_) {  // T3: next tile staging issued before compute
      char* nK = lKb + (cur ^ 1) * 8192;
      char* nV = lVb + (cur ^ 1) * 8192;
      for (int c = 0; c < 2; ++c) {
        unsigned o = w * 2048 + c * 1024 + lane * 16;
        unsigned u = swz128(o);
        gload_lds16(Kb + (size_t)(kv0 + 64 + (u >> 7)) * (D_ * 2) + (u & 127),
                    nK + w * 2048 + c * 1024);
        gload_lds16(Vb + (size_t)(u >> 7) * (S_ * 2) + (size_t)(kv0 + 64) * 2 + (u & 127),
                    nV + w * 2048 + c * 1024);
      }
    }
    // S^T = K Q^T: s[j][r] = S[kv=j*16+g*4+r][q=w*16+c16]
    f32x4 s[4] = {};
    for (int ks = 0; ks < 2; ++ks)
      for (int j = 0; j < 4; ++j) {
        unsigned row = j * 16 + c16;
        unsigned o = row * 128 + ks * 64 + g * 16;
        bf16x8 kf = *(const bf16x8*)(curK + swz128(o));
        s[j] = __builtin_amdgcn_mfma_f32_16x16x32_bf16(kf, qf[ks], s[j], 0, 0, 0);
      }
    float rm = s[0][0];
    for (int j = 0; j < 4; ++j)
      for (int r = 0; r < 4; ++r) rm = fmaxf(rm, s[j][r]);
    rm = fmaxf(rm, __shfl_xor(rm, 16));
    rm = fmaxf(rm, __shfl_xor(rm, 32));
    // T13 defer-rescale
    if (!__all((rm - m_run) * SC2 <= 8.0f)) {
      float mn = fmaxf(m_run, rm);
      float sc = exp2f((m_run - mn) * SC2);
      l_run *= sc;
      for (int i = 0; i < 4; ++i) oacc[i] *= sc;
      m_run = mn;
    }
    float rs = 0.f;
    unsigned qrow = w * 16 + c16;
    for (int j = 0; j < 4; ++j) {
      float p0 = exp2f((s[j][0] - m_run) * SC2);
      float p1 = exp2f((s[j][1] - m_run) * SC2);
      float p2 = exp2f((s[j][2] - m_run) * SC2);
      float p3 = exp2f((s[j][3] - m_run) * SC2);
      rs += (p0 + p1) + (p2 + p3);
      unsigned w0 = cvtpk(p0, p1);
      unsigned w1 = cvtpk(p2, p3);
      unsigned o = qrow * 128 + (unsigned)(j * 16 + g * 4) * 2;
      *(u64*)(lPb + swz128(o)) = (u64)w0 | ((u64)w1 << 32);
    }
    rs += __shfl_xor(rs, 16);
    rs += __shfl_xor(rs, 32);
    l_run += rs;
    // O^T += V^T P
    for (int ks = 0; ks < 2; ++ks) {
      unsigned po = qrow * 128 + ks * 64 + g * 16;
      bf16x8 pf = *(const bf16x8*)(lPb + swz128(po));
      for (int i = 0; i < 4; ++i) {
        unsigned vo = (unsigned)(i * 16 + c16) * 128 + ks * 64 + g * 16;
        bf16x8 vf = *(const bf16x8*)(curV + swz128(vo));
        oacc[i] = __builtin_amdgcn_mfma_f32_16x16x32_bf16(vf, pf, oacc[i], 0, 0, 0);
      }
    }
    asm volatile("s_waitcnt vmcnt(0)" ::: "memory");
    __syncthreads();
  }
  float inv = 1.f / l_run;
  int q = q0 + w * 16 + c16;
  u16* orow = O + (size_t)(b * S_ + q) * D_ + h * 64;
  for (int i = 0; i < 4; ++i) {
    unsigned e0 = cvtpk(oacc[i][0] * inv, oacc[i][1] * inv);
    unsigned e1 = cvtpk(oacc[i][2] * inv, oacc[i][3] * inv);
    *(u64*)(orow + i * 16 + g * 4) = (u64)e0 | ((u64)e1 << 32);
  }
}

extern "C" void kernel_launch(void* const* d_in, const int* in_sizes, int n_in,
                              void* d_out, int out_size, void* d_ws, size_t ws_size,
                              hipStream_t stream) {
  const float* q_in = (const float*)d_in[0];
  const float* k_in = (const float*)d_in[1];
  const float* v_in = (const float*)d_in[2];
  const float* Wq = (const float*)d_in[3];
  const float* Wk = (const float*)d_in[4];
  const float* Wv = (const float*)d_in[5];
  const float* Wo = (const float*)d_in[6];
  u16* ws = (u16*)d_ws;
  const size_t WSZ = (size_t)1024 * 1024;
  const size_t TSZ = (size_t)B_ * S_ * D_;  // 4,194,304
  u16* WqT = ws;
  u16* WkT = ws + WSZ;
  u16* WvT = ws + 2 * WSZ;
  u16* WoT = ws + 3 * WSZ;
  u16* Qb = ws + 4 * WSZ;
  u16* Kb = Qb + TSZ;
  u16* Vb = Kb + TSZ;
  u16* VTb = Vb + TSZ;
  u16* Ob = VTb + TSZ;
  dim3 tb(256);
  T4 tw = {{Wq, Wk, Wv, Wo}, {WqT, WkT, WvT, WoT}};
  transpose_w4<<<dim3(16, 16, 4), tb, 0, stream>>>(tw);
  QKV gq = {{q_in, k_in, v_in}, {WqT, WkT, WvT}, {Qb, Kb, Vb}};
  gemm_qkv<<<dim3(32, 8, 3), tb, 0, stream>>>(gq);
  transpose_v<<<dim3(32, 32), tb, 0, stream>>>(Vb, VTb);
  flash_attn<<<dim3(S_ / 64, B_ * H_), tb, 0, stream>>>(Qb, Kb, VTb, Ob);
  gemm_bt_f32<<<dim3(32, 16), tb, 0, stream>>>(Ob, WoT, (float*)d_out);
}